// Round 2
// baseline (5599.573 us; speedup 1.0000x reference)
//
#include <hip/hip_runtime.h>

typedef unsigned short u16;
typedef __attribute__((ext_vector_type(8))) short short8;
typedef __attribute__((ext_vector_type(8))) __bf16 bf16x8;
typedef __attribute__((ext_vector_type(4))) float f32x4;

#define DEV __device__ __forceinline__

// ---------- scalar helpers ----------
DEV u16 f2bf(float f){ unsigned u = __float_as_uint(f); return (u16)((u + 0x7fffu + ((u>>16)&1u)) >> 16); }
DEV float bf2f(u16 h){ return __uint_as_float(((unsigned)h)<<16); }

DEV f32x4 mfma_bf16(short8 a, short8 b, f32x4 c){
  return __builtin_amdgcn_mfma_f32_16x16x32_bf16(
      __builtin_bit_cast(bf16x8, a), __builtin_bit_cast(bf16x8, b), c, 0, 0, 0);
}

DEV void gl2lds16(const u16* g, u16* s){
  __builtin_amdgcn_global_load_lds(
      (__attribute__((address_space(1))) void*)(g),
      (__attribute__((address_space(3))) void*)(s), 16, 0, 0);
}

// problem constants
#define BB 8
#define HH 48
#define WW 192
#define CC 512
#define NTOK (BB*HH*WW)        // 73728

// ---------- weight prep ----------
__global__ void k_permqkv(const float* __restrict__ w, u16* __restrict__ o){
  int i = blockIdx.x*256 + threadIdx.x;          // 1536*512 total
  int n = i >> 9, kk = i & 511;
  int src = 3*(n & 511) + (n >> 9);
  o[i] = f2bf(w[src*512 + kk]);
}
__global__ void k_conv(const float* __restrict__ w, u16* __restrict__ o, int nelem){
  int i = blockIdx.x*256 + threadIdx.x;
  if (i < nelem) o[i] = f2bf(w[i]);
}

// ---------- transpose in: x (B,C,H,W) f32 -> xres (B,H,W,C) f32 ----------
__global__ void k_tin(const float* __restrict__ x, float* __restrict__ xr){
  __shared__ float T[32][33];
  int bh = blockIdx.x / 96, rem = blockIdx.x % 96;
  int c0 = (rem/6)*32, w0 = (rem%6)*32;
  int b = bh / HH, h = bh % HH;
  const float* xp = x + ((size_t)b*CC*HH + h)*WW;     // + c*(HH*WW) + w
  #pragma unroll
  for (int p=0;p<4;p++){
    int idx = p*256 + threadIdx.x;
    int cc = idx >> 5, ww = idx & 31;
    T[cc][ww] = xp[(size_t)(c0+cc)*(HH*WW) + w0 + ww];
  }
  __syncthreads();
  float* xo = xr + (size_t)bh*WW*CC;
  #pragma unroll
  for (int p=0;p<4;p++){
    int idx = p*256 + threadIdx.x;
    int ww = idx >> 5, cc = idx & 31;
    xo[(size_t)(w0+ww)*CC + c0 + cc] = T[cc][ww];
  }
}

// ---------- transpose out: xres (B,H,W,C) f32 -> out (B,C,H,W) f32 ----------
__global__ void k_tout(const float* __restrict__ xr, float* __restrict__ out){
  __shared__ float T[32][33];
  int bh = blockIdx.x / 96, rem = blockIdx.x % 96;
  int c0 = (rem/6)*32, w0 = (rem%6)*32;
  int b = bh / HH, h = bh % HH;
  const float* xi = xr + (size_t)bh*WW*CC;
  #pragma unroll
  for (int p=0;p<4;p++){
    int idx = p*256 + threadIdx.x;
    int ww = idx >> 5, cc = idx & 31;
    T[ww][cc] = xi[(size_t)(w0+ww)*CC + c0 + cc];
  }
  __syncthreads();
  float* op = out + ((size_t)b*CC*HH + h)*WW;
  #pragma unroll
  for (int p=0;p<4;p++){
    int idx = p*256 + threadIdx.x;
    int cc = idx >> 5, ww = idx & 31;
    op[(size_t)(c0+cc)*(HH*WW) + w0 + ww] = T[ww][cc];
  }
}

// ---------- LayerNorm: xres f32 -> y bf16 (wave per token) ----------
__global__ void k_ln(const float* __restrict__ xr, const float* __restrict__ g,
                     const float* __restrict__ bb, u16* __restrict__ y){
  int t = blockIdx.x*4 + (threadIdx.x>>6);
  int lane = threadIdx.x & 63;
  const float* row = xr + (size_t)t*CC + lane*8;
  float v[8];
  *(f32x4*)(v)   = *(const f32x4*)(row);
  *(f32x4*)(v+4) = *(const f32x4*)(row+4);
  float s=0.f, s2=0.f;
  #pragma unroll
  for (int j=0;j<8;j++){ s += v[j]; s2 += v[j]*v[j]; }
  #pragma unroll
  for (int o=32;o;o>>=1){ s += __shfl_xor(s,o); s2 += __shfl_xor(s2,o); }
  float mean = s*(1.f/CC);
  float var  = s2*(1.f/CC) - mean*mean;
  float rs = rsqrtf(var + 1e-5f);
  const float* gp = g + lane*8; const float* bp = bb + lane*8;
  short8 o8;
  #pragma unroll
  for (int j=0;j<8;j++) o8[j] = (short)f2bf((v[j]-mean)*rs*gp[j] + bp[j]);
  *(short8*)(y + (size_t)t*CC + lane*8) = o8;
}

// ---------- GEMM: Out(M x N) = A(M x K) @ Bw(N x K)^T ----------
// epi 0: store bf16 ; epi 1: store bf16 with bias+relu ; epi 2: f32 Out += acc (+bias)
__global__ __launch_bounds__(256)
void k_gemm(const u16* __restrict__ A, int lda,
            const u16* __restrict__ Bw, int ldb,
            void* __restrict__ Out, int ldo,
            const float* __restrict__ bias,
            int K, int nbn, int epi){
  __shared__ __align__(16) u16 As[128*32];
  __shared__ __align__(16) u16 Bs[128*32];
  int mb = blockIdx.x / nbn, nb = blockIdx.x % nbn;
  int tid = threadIdx.x, lane = tid & 63, wv = tid >> 6;
  size_t m0 = (size_t)mb*128, n0 = (size_t)nb*128;
  const u16* gA = A  + (m0 + wv*32 + (lane>>2))*(size_t)lda + (lane&3)*8;
  const u16* gB = Bw + (n0 + wv*32 + (lane>>2))*(size_t)ldb + (lane&3)*8;
  u16* sA = As + wv*1024;
  u16* sB = Bs + wv*1024;
  int m = lane & 15, quad = lane >> 4;
  int wm = (wv>>1)*64, wn = (wv&1)*64;
  f32x4 acc[4][4];
  #pragma unroll
  for (int i=0;i<4;i++)
    #pragma unroll
    for (int j=0;j<4;j++) acc[i][j] = (f32x4){0.f,0.f,0.f,0.f};
  const u16* aB = As + (wm + m)*32 + quad*8;
  const u16* bB = Bs + (wn + m)*32 + quad*8;
  for (int k0 = 0; k0 < K; k0 += 32){
    gl2lds16(gA,                  sA);
    gl2lds16(gA + 16*(size_t)lda, sA + 512);
    gl2lds16(gB,                  sB);
    gl2lds16(gB + 16*(size_t)ldb, sB + 512);
    gA += 32; gB += 32;
    __syncthreads();
    short8 af[4], bf[4];
    #pragma unroll
    for (int i=0;i<4;i++) af[i] = *(const short8*)(aB + i*16*32);
    #pragma unroll
    for (int j=0;j<4;j++) bf[j] = *(const short8*)(bB + j*16*32);
    #pragma unroll
    for (int i=0;i<4;i++)
      #pragma unroll
      for (int j=0;j<4;j++)
        acc[i][j] = mfma_bf16(af[i], bf[j], acc[i][j]);
    __syncthreads();
  }
  if (epi == 2){
    float* O = (float*)Out + (m0 + wm + quad*4)*(size_t)ldo + n0 + wn + m;
    #pragma unroll
    for (int j=0;j<4;j++){
      float bv = bias ? bias[n0 + wn + j*16 + m] : 0.f;
      #pragma unroll
      for (int i=0;i<4;i++)
        #pragma unroll
        for (int r=0;r<4;r++)
          O[(size_t)(i*16+r)*ldo + j*16] += acc[i][j][r] + bv;
    }
  } else {
    u16* O = (u16*)Out + (m0 + wm + quad*4)*(size_t)ldo + n0 + wn + m;
    #pragma unroll
    for (int j=0;j<4;j++){
      float bv = bias ? bias[n0 + wn + j*16 + m] : 0.f;
      #pragma unroll
      for (int i=0;i<4;i++)
        #pragma unroll
        for (int r=0;r<4;r++){
          float v = acc[i][j][r] + bv;
          if (epi == 1) v = fmaxf(v, 0.f);
          O[(size_t)(i*16+r)*ldo + j*16] = f2bf(v);
        }
    }
  }
}

// ---------- QK^T: one wave per 16x16 S tile ----------
__global__ void k_qk(const u16* __restrict__ q, const u16* __restrict__ kp, int ldq,
                     float* __restrict__ S, int L, int nt,
                     int SD, int OUTs, int INN, int LST, float scale){
  int blk = blockIdx.x;
  int s = blk / (nt*nt), tl = blk % (nt*nt);
  int ti = tl / nt, tj = tl % nt;
  int lane = threadIdx.x, m = lane & 15, quad = lane >> 4;
  size_t tokbase = (size_t)(s/SD)*OUTs + (size_t)(s%SD)*INN;
  const u16* qr = q  + (tokbase + (size_t)(ti*16+m)*LST)*ldq + quad*8;
  const u16* kr = kp + (tokbase + (size_t)(tj*16+m)*LST)*ldq + quad*8;
  f32x4 acc = (f32x4){0.f,0.f,0.f,0.f};
  #pragma unroll
  for (int kk=0; kk<CC; kk+=32)
    acc = mfma_bf16(*(const short8*)(qr+kk), *(const short8*)(kr+kk), acc);
  float* Sp = S + (size_t)s*L*L + (size_t)(ti*16 + quad*4)*L + tj*16 + m;
  #pragma unroll
  for (int r=0;r<4;r++) Sp[(size_t)r*L] = acc[r]*scale;
}

// ---------- softmax rows (wave per row), write bf16 P padded to Lp ----------
__global__ void k_softmax(const float* __restrict__ S, u16* __restrict__ P, int L, int Lp){
  int row = blockIdx.x*4 + (threadIdx.x>>6);
  int lane = threadIdx.x & 63;
  const float* sr = S + (size_t)row*L;
  float v0 = (lane      < L) ? sr[lane]      : -3.0e38f;
  float v1 = (lane+64   < L) ? sr[lane+64]   : -3.0e38f;
  float v2 = (lane+128  < L) ? sr[lane+128]  : -3.0e38f;
  float mx = fmaxf(v0, fmaxf(v1, v2));
  #pragma unroll
  for (int o=32;o;o>>=1) mx = fmaxf(mx, __shfl_xor(mx, o));
  float e0 = (lane      < L) ? __expf(v0-mx) : 0.f;
  float e1 = (lane+64   < L) ? __expf(v1-mx) : 0.f;
  float e2 = (lane+128  < L) ? __expf(v2-mx) : 0.f;
  float sm = e0+e1+e2;
  #pragma unroll
  for (int o=32;o;o>>=1) sm += __shfl_xor(sm, o);
  float inv = 1.f/sm;
  u16* pr = P + (size_t)row*Lp;
  if (lane      < Lp) pr[lane]      = f2bf(e0*inv);
  if (lane+64   < Lp) pr[lane+64]   = f2bf(e1*inv);
  if (lane+128  < Lp) pr[lane+128]  = f2bf(e2*inv);
}

// ---------- V transpose per sequence: v rows (l,c) -> vt[s][c][l], zero-pad l to Lp ----------
__global__ void k_vt(const u16* __restrict__ v, int ldv, u16* __restrict__ vt,
                     int L, int Lp, int SD, int OUTs, int INN, int LST){
  __shared__ float T[32*193];
  int s = blockIdx.x >> 4;
  int c0 = (blockIdx.x & 15)*32;
  size_t tokbase = (size_t)(s/SD)*OUTs + (size_t)(s%SD)*INN;
  int pad = Lp + 1;
  for (int idx = threadIdx.x; idx < L*32; idx += 256){
    int l = idx >> 5, cc = idx & 31;
    T[cc*pad + l] = bf2f(v[(tokbase + (size_t)l*LST)*ldv + c0 + cc]);
  }
  __syncthreads();
  u16* vo = vt + ((size_t)s*CC + c0)*Lp;
  for (int idx = threadIdx.x; idx < 32*Lp; idx += 256){
    int cc = idx / Lp, l = idx - cc*Lp;
    vo[idx] = (l < L) ? f2bf(T[cc*pad + l]) : (u16)0;
  }
}

// ---------- PV: wave per (seq, 16-row q tile), loops 32 col tiles ----------
__global__ void k_pv(const u16* __restrict__ P, const u16* __restrict__ vt, u16* __restrict__ ctx,
                     int L, int Lp, int ntq, int SD, int OUTs, int INN, int LST){
  int s = blockIdx.x / ntq, qt = blockIdx.x % ntq;
  int lane = threadIdx.x, m = lane & 15, quad = lane >> 4;
  int nks = Lp >> 5;
  short8 a[6];
  const u16* pr = P + ((size_t)s*L + qt*16 + m)*Lp + quad*8;
  for (int ks=0; ks<nks; ks++) a[ks] = *(const short8*)(pr + ks*32);
  size_t tokbase = (size_t)(s/SD)*OUTs + (size_t)(s%SD)*INN;
  const u16* vb = vt + ((size_t)s*CC + m)*Lp + quad*8;
  for (int cj=0; cj<32; cj++){
    f32x4 acc = (f32x4){0.f,0.f,0.f,0.f};
    const u16* vr = vb + (size_t)cj*16*Lp;
    for (int ks=0; ks<nks; ks++)
      acc = mfma_bf16(a[ks], *(const short8*)(vr + ks*32), acc);
    u16* cp = ctx + (tokbase + (size_t)(qt*16 + quad*4)*LST)*CC + cj*16 + m;
    #pragma unroll
    for (int r=0;r<4;r++) cp[(size_t)r*LST*CC] = f2bf(acc[r]);
  }
}

// =======================================================================
extern "C" void kernel_launch(void* const* d_in, const int* in_sizes, int n_in,
                              void* d_out, int out_size, void* d_ws, size_t ws_size,
                              hipStream_t stream){
  const float* x      = (const float*)d_in[0];
  const float* wqkv1  = (const float*)d_in[1];
  const float* wout1  = (const float*)d_in[2];
  const float* wqkv2  = (const float*)d_in[3];
  const float* wout2  = (const float*)d_in[4];
  const float* g1 = (const float*)d_in[5];  const float* b1 = (const float*)d_in[6];
  const float* g2 = (const float*)d_in[7];  const float* b2 = (const float*)d_in[8];
  const float* g3 = (const float*)d_in[9];  const float* b3 = (const float*)d_in[10];
  const float* wfc1 = (const float*)d_in[11]; const float* bfc1 = (const float*)d_in[12];
  const float* wfc2 = (const float*)d_in[13]; const float* bfc2 = (const float*)d_in[14];

  // ---- workspace layout (461 MB total; fits well under d_ws) ----
  char* ws = (char*)d_ws;
  size_t off = 0;
  auto alloc = [&](size_t bytes)->char*{
    char* p = ws + off; off += (bytes + 255) & ~(size_t)255; return p;
  };
  float* xres = (float*)alloc((size_t)NTOK*CC*4);            // 151.0 MB residual (f32)
  u16*   y    = (u16*)  alloc((size_t)NTOK*CC*2);            //  75.5 MB LN out / ctx
  u16*   qkv  = (u16*)  alloc((size_t)NTOK*1536*2);          // 226.5 MB q|k|v ; MLP h overlays
  u16* wqkv1p = (u16*)alloc((size_t)1536*512*2);
  u16* wqkv2p = (u16*)alloc((size_t)1536*512*2);
  u16* wout1p = (u16*)alloc((size_t)512*512*2);
  u16* wout2p = (u16*)alloc((size_t)512*512*2);
  u16* wfc1p  = (u16*)alloc((size_t)2048*512*2);
  u16* wfc2p  = (u16*)alloc((size_t)512*2048*2);
  u16*   hv   = qkv;                                         // MLP hidden (151 MB <= 226.5 MB)

  // ---- d_out doubles as scratch (fully rewritten by k_tout at the end) ----
  // P @ 0 (28.3 MB) ; vt @ 28.3 MB (<=100.7 MB) ; S aliases vt region (S dead
  // before k_vt writes, stream-ordered). Peak 129.0 MB <= 151.0 MB d_out.
  u16*   P    = (u16*)d_out;
  u16*   vt   = (u16*)((char*)d_out + 28311552);
  float* S    = (float*)((char*)d_out + 28311552);
  (void)ws_size; (void)in_sizes; (void)n_in; (void)out_size;

  const float scale = 0.044194173824159216f;   // 1/sqrt(512)

  // weights
  k_permqkv<<<3072, 256, 0, stream>>>(wqkv1, wqkv1p);
  k_permqkv<<<3072, 256, 0, stream>>>(wqkv2, wqkv2p);
  k_conv<<<1024, 256, 0, stream>>>(wout1, wout1p, 512*512);
  k_conv<<<1024, 256, 0, stream>>>(wout2, wout2p, 512*512);
  k_conv<<<4096, 256, 0, stream>>>(wfc1, wfc1p, 2048*512);
  k_conv<<<4096, 256, 0, stream>>>(wfc2, wfc2p, 512*2048);

  // stage 0: layout
  k_tin<<<BB*HH*96, 256, 0, stream>>>(x, xres);

  // ---- attention 1 (along H; seq = (b,w), L=48) ----
  k_ln<<<NTOK/4, 256, 0, stream>>>(xres, g1, b1, y);
  k_gemm<<<576*12, 256, 0, stream>>>(y, 512, wqkv1p, 512, qkv, 1536, nullptr, 512, 12, 0);
  k_qk<<<1536*9, 64, 0, stream>>>(qkv, qkv+512, 1536, S, 48, 3, 192, 9216, 1, 192, scale);
  k_softmax<<<NTOK/4, 256, 0, stream>>>(S, P, 48, 64);
  k_vt<<<1536*16, 256, 0, stream>>>(qkv+1024, 1536, vt, 48, 64, 192, 9216, 1, 192);
  k_pv<<<1536*3, 64, 0, stream>>>(P, vt, y, 48, 64, 3, 192, 9216, 1, 192);
  k_gemm<<<576*4, 256, 0, stream>>>(y, 512, wout1p, 512, xres, 512, nullptr, 512, 4, 2);

  // ---- attention 2 (along W; seq = (b,h), L=192) ----
  k_ln<<<NTOK/4, 256, 0, stream>>>(xres, g2, b2, y);
  k_gemm<<<576*12, 256, 0, stream>>>(y, 512, wqkv2p, 512, qkv, 1536, nullptr, 512, 12, 0);
  k_qk<<<384*144, 64, 0, stream>>>(qkv, qkv+512, 1536, S, 192, 12, 48, 9216, 192, 1, scale);
  k_softmax<<<NTOK/4, 256, 0, stream>>>(S, P, 192, 192);
  k_vt<<<384*16, 256, 0, stream>>>(qkv+1024, 1536, vt, 192, 192, 48, 9216, 192, 1);
  k_pv<<<384*12, 64, 0, stream>>>(P, vt, y, 192, 192, 12, 48, 9216, 192, 1);
  k_gemm<<<576*4, 256, 0, stream>>>(y, 512, wout2p, 512, xres, 512, nullptr, 512, 4, 2);

  // ---- MLP (two K-chunks of 1024 over the 2048 hidden dim) ----
  k_ln<<<NTOK/4, 256, 0, stream>>>(xres, g3, b3, y);
  // chunk 0
  k_gemm<<<576*8, 256, 0, stream>>>(y, 512, wfc1p, 512, hv, 1024, bfc1, 512, 8, 1);
  k_gemm<<<576*4, 256, 0, stream>>>(hv, 1024, wfc2p, 2048, xres, 512, bfc2, 1024, 4, 2);
  // chunk 1
  k_gemm<<<576*8, 256, 0, stream>>>(y, 512, wfc1p + 1024*512, 512, hv, 1024, bfc1 + 1024, 512, 8, 1);
  k_gemm<<<576*4, 256, 0, stream>>>(hv, 1024, wfc2p + 1024, 2048, xres, 512, nullptr, 1024, 4, 2);

  // output layout
  k_tout<<<BB*HH*96, 256, 0, stream>>>(xres, (float*)d_out);
}

// Round 3
// 2462.127 us; speedup vs baseline: 2.2743x; 2.2743x over previous
//
#include <hip/hip_runtime.h>

typedef unsigned short u16;
typedef __attribute__((ext_vector_type(8))) short short8;
typedef __attribute__((ext_vector_type(8))) __bf16 bf16x8;
typedef __attribute__((ext_vector_type(4))) float f32x4;

#define DEV __device__ __forceinline__

// ---------- scalar helpers ----------
DEV u16 f2bf(float f){ unsigned u = __float_as_uint(f); return (u16)((u + 0x7fffu + ((u>>16)&1u)) >> 16); }
DEV float bf2f(u16 h){ return __uint_as_float(((unsigned)h)<<16); }

DEV f32x4 mfma_bf16(short8 a, short8 b, f32x4 c){
  return __builtin_amdgcn_mfma_f32_16x16x32_bf16(
      __builtin_bit_cast(bf16x8, a), __builtin_bit_cast(bf16x8, b), c, 0, 0, 0);
}

DEV void gl2lds16(const u16* g, u16* s){
  __builtin_amdgcn_global_load_lds(
      (__attribute__((address_space(1))) void*)(g),
      (__attribute__((address_space(3))) void*)(s), 16, 0, 0);
}

// problem constants
#define BB 8
#define HH 48
#define WW 192
#define CC 512
#define NTOK (BB*HH*WW)        // 73728

// ---------- weight prep ----------
__global__ void k_permqkv(const float* __restrict__ w, u16* __restrict__ o){
  int i = blockIdx.x*256 + threadIdx.x;          // 1536*512 total
  int n = i >> 9, kk = i & 511;
  int src = 3*(n & 511) + (n >> 9);
  o[i] = f2bf(w[src*512 + kk]);
}
__global__ void k_conv(const float* __restrict__ w, u16* __restrict__ o, int nelem){
  int i = blockIdx.x*256 + threadIdx.x;
  if (i < nelem) o[i] = f2bf(w[i]);
}

// ---------- transpose in: x (B,C,H,W) f32 -> xres (B,H,W,C) f32 ----------
__global__ void k_tin(const float* __restrict__ x, float* __restrict__ xr){
  __shared__ float T[32][33];
  int bh = blockIdx.x / 96, rem = blockIdx.x % 96;
  int c0 = (rem/6)*32, w0 = (rem%6)*32;
  int b = bh / HH, h = bh % HH;
  const float* xp = x + ((size_t)b*CC*HH + h)*WW;     // + c*(HH*WW) + w
  #pragma unroll
  for (int p=0;p<4;p++){
    int idx = p*256 + threadIdx.x;
    int cc = idx >> 5, ww = idx & 31;
    T[cc][ww] = xp[(size_t)(c0+cc)*(HH*WW) + w0 + ww];
  }
  __syncthreads();
  float* xo = xr + (size_t)bh*WW*CC;
  #pragma unroll
  for (int p=0;p<4;p++){
    int idx = p*256 + threadIdx.x;
    int ww = idx >> 5, cc = idx & 31;
    xo[(size_t)(w0+ww)*CC + c0 + cc] = T[cc][ww];
  }
}

// ---------- transpose out: xres (B,H,W,C) f32 -> out (B,C,H,W) f32 ----------
__global__ void k_tout(const float* __restrict__ xr, float* __restrict__ out){
  __shared__ float T[32][33];
  int bh = blockIdx.x / 96, rem = blockIdx.x % 96;
  int c0 = (rem/6)*32, w0 = (rem%6)*32;
  int b = bh / HH, h = bh % HH;
  const float* xi = xr + (size_t)bh*WW*CC;
  #pragma unroll
  for (int p=0;p<4;p++){
    int idx = p*256 + threadIdx.x;
    int ww = idx >> 5, cc = idx & 31;
    T[ww][cc] = xi[(size_t)(w0+ww)*CC + c0 + cc];
  }
  __syncthreads();
  float* op = out + ((size_t)b*CC*HH + h)*WW;
  #pragma unroll
  for (int p=0;p<4;p++){
    int idx = p*256 + threadIdx.x;
    int cc = idx >> 5, ww = idx & 31;
    op[(size_t)(c0+cc)*(HH*WW) + w0 + ww] = T[ww][cc];
  }
}

// ---------- LayerNorm: xres f32 -> y bf16 (wave per token) ----------
__global__ void k_ln(const float* __restrict__ xr, const float* __restrict__ g,
                     const float* __restrict__ bb, u16* __restrict__ y){
  int t = blockIdx.x*4 + (threadIdx.x>>6);
  int lane = threadIdx.x & 63;
  const float* row = xr + (size_t)t*CC + lane*8;
  float v[8];
  *(f32x4*)(v)   = *(const f32x4*)(row);
  *(f32x4*)(v+4) = *(const f32x4*)(row+4);
  float s=0.f, s2=0.f;
  #pragma unroll
  for (int j=0;j<8;j++){ s += v[j]; s2 += v[j]*v[j]; }
  #pragma unroll
  for (int o=32;o;o>>=1){ s += __shfl_xor(s,o); s2 += __shfl_xor(s2,o); }
  float mean = s*(1.f/CC);
  float var  = s2*(1.f/CC) - mean*mean;
  float rs = rsqrtf(var + 1e-5f);
  const float* gp = g + lane*8; const float* bp = bb + lane*8;
  short8 o8;
  #pragma unroll
  for (int j=0;j<8;j++) o8[j] = (short)f2bf((v[j]-mean)*rs*gp[j] + bp[j]);
  *(short8*)(y + (size_t)t*CC + lane*8) = o8;
}

// ---------- GEMM: Out(M x N) = A(M x K) @ Bw(N x K)^T ----------
// epi 0: store bf16 ; epi 1: store bf16 with bias+relu ; epi 2: f32 Out += acc (+bias)
__global__ __launch_bounds__(256)
void k_gemm(const u16* __restrict__ A, int lda,
            const u16* __restrict__ Bw, int ldb,
            void* __restrict__ Out, int ldo,
            const float* __restrict__ bias,
            int K, int nbn, int epi){
  __shared__ __align__(16) u16 As[128*32];
  __shared__ __align__(16) u16 Bs[128*32];
  int mb = blockIdx.x / nbn, nb = blockIdx.x % nbn;
  int tid = threadIdx.x, lane = tid & 63, wv = tid >> 6;
  size_t m0 = (size_t)mb*128, n0 = (size_t)nb*128;
  const u16* gA = A  + (m0 + wv*32 + (lane>>2))*(size_t)lda + (lane&3)*8;
  const u16* gB = Bw + (n0 + wv*32 + (lane>>2))*(size_t)ldb + (lane&3)*8;
  u16* sA = As + wv*1024;
  u16* sB = Bs + wv*1024;
  int m = lane & 15, quad = lane >> 4;
  int wm = (wv>>1)*64, wn = (wv&1)*64;
  f32x4 acc[4][4];
  #pragma unroll
  for (int i=0;i<4;i++)
    #pragma unroll
    for (int j=0;j<4;j++) acc[i][j] = (f32x4){0.f,0.f,0.f,0.f};
  const u16* aB = As + (wm + m)*32 + quad*8;
  const u16* bB = Bs + (wn + m)*32 + quad*8;
  for (int k0 = 0; k0 < K; k0 += 32){
    gl2lds16(gA,                  sA);
    gl2lds16(gA + 16*(size_t)lda, sA + 512);
    gl2lds16(gB,                  sB);
    gl2lds16(gB + 16*(size_t)ldb, sB + 512);
    gA += 32; gB += 32;
    __syncthreads();
    short8 af[4], bf[4];
    #pragma unroll
    for (int i=0;i<4;i++) af[i] = *(const short8*)(aB + i*16*32);
    #pragma unroll
    for (int j=0;j<4;j++) bf[j] = *(const short8*)(bB + j*16*32);
    #pragma unroll
    for (int i=0;i<4;i++)
      #pragma unroll
      for (int j=0;j<4;j++)
        acc[i][j] = mfma_bf16(af[i], bf[j], acc[i][j]);
    __syncthreads();
  }
  if (epi == 2){
    float* O = (float*)Out + (m0 + wm + quad*4)*(size_t)ldo + n0 + wn + m;
    #pragma unroll
    for (int j=0;j<4;j++){
      float bv = bias ? bias[n0 + wn + j*16 + m] : 0.f;
      #pragma unroll
      for (int i=0;i<4;i++)
        #pragma unroll
        for (int r=0;r<4;r++)
          O[(size_t)(i*16+r)*ldo + j*16] += acc[i][j][r] + bv;
    }
  } else {
    u16* O = (u16*)Out + (m0 + wm + quad*4)*(size_t)ldo + n0 + wn + m;
    #pragma unroll
    for (int j=0;j<4;j++){
      float bv = bias ? bias[n0 + wn + j*16 + m] : 0.f;
      #pragma unroll
      for (int i=0;i<4;i++)
        #pragma unroll
        for (int r=0;r<4;r++){
          float v = acc[i][j][r] + bv;
          if (epi == 1) v = fmaxf(v, 0.f);
          O[(size_t)(i*16+r)*ldo + j*16] = f2bf(v);
        }
    }
  }
}

// ---------- QK^T: one wave per 16x16 S tile ----------
__global__ void k_qk(const u16* __restrict__ q, const u16* __restrict__ kp, int ldq,
                     float* __restrict__ S, int L, int nt,
                     int SD, int OUTs, int INN, int LST, float scale){
  int blk = blockIdx.x;
  int s = blk / (nt*nt), tl = blk % (nt*nt);
  int ti = tl / nt, tj = tl % nt;
  int lane = threadIdx.x, m = lane & 15, quad = lane >> 4;
  size_t tokbase = (size_t)(s/SD)*OUTs + (size_t)(s%SD)*INN;
  const u16* qr = q  + (tokbase + (size_t)(ti*16+m)*LST)*ldq + quad*8;
  const u16* kr = kp + (tokbase + (size_t)(tj*16+m)*LST)*ldq + quad*8;
  f32x4 acc = (f32x4){0.f,0.f,0.f,0.f};
  #pragma unroll
  for (int kk=0; kk<CC; kk+=32)
    acc = mfma_bf16(*(const short8*)(qr+kk), *(const short8*)(kr+kk), acc);
  float* Sp = S + (size_t)s*L*L + (size_t)(ti*16 + quad*4)*L + tj*16 + m;
  #pragma unroll
  for (int r=0;r<4;r++) Sp[(size_t)r*L] = acc[r]*scale;
}

// ---------- softmax rows (wave per row), write bf16 P padded to Lp ----------
__global__ void k_softmax(const float* __restrict__ S, u16* __restrict__ P, int L, int Lp){
  int row = blockIdx.x*4 + (threadIdx.x>>6);
  int lane = threadIdx.x & 63;
  const float* sr = S + (size_t)row*L;
  float v0 = (lane      < L) ? sr[lane]      : -3.0e38f;
  float v1 = (lane+64   < L) ? sr[lane+64]   : -3.0e38f;
  float v2 = (lane+128  < L) ? sr[lane+128]  : -3.0e38f;
  float mx = fmaxf(v0, fmaxf(v1, v2));
  #pragma unroll
  for (int o=32;o;o>>=1) mx = fmaxf(mx, __shfl_xor(mx, o));
  float e0 = (lane      < L) ? __expf(v0-mx) : 0.f;
  float e1 = (lane+64   < L) ? __expf(v1-mx) : 0.f;
  float e2 = (lane+128  < L) ? __expf(v2-mx) : 0.f;
  float sm = e0+e1+e2;
  #pragma unroll
  for (int o=32;o;o>>=1) sm += __shfl_xor(sm, o);
  float inv = 1.f/sm;
  u16* pr = P + (size_t)row*Lp;
  if (lane      < Lp) pr[lane]      = f2bf(e0*inv);
  if (lane+64   < Lp) pr[lane+64]   = f2bf(e1*inv);
  if (lane+128  < Lp) pr[lane+128]  = f2bf(e2*inv);
}

// ---------- V transpose per sequence: v rows (l,c) -> vt[s][c][l], zero-pad l to Lp ----------
__global__ void k_vt(const u16* __restrict__ v, int ldv, u16* __restrict__ vt,
                     int L, int Lp, int SD, int OUTs, int INN, int LST){
  __shared__ float T[32*193];
  int s = blockIdx.x >> 4;
  int c0 = (blockIdx.x & 15)*32;
  size_t tokbase = (size_t)(s/SD)*OUTs + (size_t)(s%SD)*INN;
  int pad = Lp + 1;
  for (int idx = threadIdx.x; idx < L*32; idx += 256){
    int l = idx >> 5, cc = idx & 31;
    T[cc*pad + l] = bf2f(v[(tokbase + (size_t)l*LST)*ldv + c0 + cc]);
  }
  __syncthreads();
  u16* vo = vt + ((size_t)s*CC + c0)*Lp;
  for (int idx = threadIdx.x; idx < 32*Lp; idx += 256){
    int cc = idx / Lp, l = idx - cc*Lp;
    vo[idx] = (l < L) ? f2bf(T[cc*pad + l]) : (u16)0;
  }
}

// ---------- PV v2: block (256 thr) per (seq, column-group) with LDS staging ----------
// P staged once to LDS (padded rows); vt read exactly once chip-wide (disjoint
// cj ranges per block); ctx staged to LDS and stored as contiguous rows.
template<int L, int Lp, int NTQ, int NCJ>
__global__ __launch_bounds__(256)
void k_pv2(const u16* __restrict__ P, const u16* __restrict__ vt, u16* __restrict__ ctx,
           int SD, int OUTs, int INN, int LST){
  constexpr int G   = 32 / NCJ;          // blocks per sequence
  constexpr int LPP = Lp + 8;            // padded P row stride (u16) - bank spread
  constexpr int CW  = NCJ * 16;          // ctx columns per block
  constexpr int CJW = NCJ / 4;           // cj tiles per wave
  constexpr int NKS = Lp / 32;           // K steps per MFMA chain
  constexpr int SHW = (L*LPP > L*CW) ? L*LPP : L*CW;
  __shared__ __align__(16) u16 SH[SHW];

  int sq = blockIdx.x / G, g = blockIdx.x % G;
  int tid = threadIdx.x, lane = tid & 63, wv = tid >> 6;
  int m = lane & 15, quad = lane >> 4;

  // stage P[seq] -> LDS (coalesced, padded rows)
  const u16* Pg = P + (size_t)sq * L * Lp;
  constexpr int PU = L * Lp / 8;
  for (int u = tid; u < PU; u += 256){
    int r = u / (Lp/8), c = u % (Lp/8);
    *(short8*)(SH + r*LPP + c*8) = *(const short8*)(Pg + (size_t)r*Lp + c*8);
  }
  __syncthreads();

  // B fragments from vt (each block reads a disjoint 16*CJW*4-row slice once)
  short8 bf[CJW][NKS];
  #pragma unroll
  for (int lc = 0; lc < CJW; lc++){
    const u16* vr = vt + ((size_t)sq*CC + (size_t)((g*NCJ + (wv*CJW + lc))*16 + m))*Lp + quad*8;
    #pragma unroll
    for (int ks = 0; ks < NKS; ks++) bf[lc][ks] = *(const short8*)(vr + ks*32);
  }

  f32x4 acc[CJW][NTQ];
  #pragma unroll
  for (int lc = 0; lc < CJW; lc++)
    #pragma unroll
    for (int qt = 0; qt < NTQ; qt++) acc[lc][qt] = (f32x4){0.f,0.f,0.f,0.f};

  #pragma unroll
  for (int qt = 0; qt < NTQ; qt++){
    short8 a[NKS];
    #pragma unroll
    for (int ks = 0; ks < NKS; ks++)
      a[ks] = *(const short8*)(SH + (qt*16 + m)*LPP + quad*8 + ks*32);
    #pragma unroll
    for (int lc = 0; lc < CJW; lc++)
      #pragma unroll
      for (int ks = 0; ks < NKS; ks++)
        acc[lc][qt] = mfma_bf16(a[ks], bf[lc][ks], acc[lc][qt]);
  }
  __syncthreads();   // all P reads done -> reuse SH for ctx tile

  #pragma unroll
  for (int qt = 0; qt < NTQ; qt++)
    #pragma unroll
    for (int lc = 0; lc < CJW; lc++)
      #pragma unroll
      for (int r = 0; r < 4; r++)
        SH[(qt*16 + quad*4 + r)*CW + (wv*CJW + lc)*16 + m] = f2bf(acc[lc][qt][r]);
  __syncthreads();

  // coalesced ctx store: rows of CW u16 (>=256B contiguous)
  size_t tokbase = (size_t)(sq/SD)*OUTs + (size_t)(sq%SD)*INN;
  constexpr int CU8 = CW / 8;
  constexpr int TU = L * CU8;
  for (int u = tid; u < TU; u += 256){
    int l = u / CU8, c = u % CU8;
    *(short8*)(ctx + (tokbase + (size_t)l*LST)*CC + g*CW + c*8) =
        *(const short8*)(SH + l*CW + c*8);
  }
}

// =======================================================================
extern "C" void kernel_launch(void* const* d_in, const int* in_sizes, int n_in,
                              void* d_out, int out_size, void* d_ws, size_t ws_size,
                              hipStream_t stream){
  const float* x      = (const float*)d_in[0];
  const float* wqkv1  = (const float*)d_in[1];
  const float* wout1  = (const float*)d_in[2];
  const float* wqkv2  = (const float*)d_in[3];
  const float* wout2  = (const float*)d_in[4];
  const float* g1 = (const float*)d_in[5];  const float* b1 = (const float*)d_in[6];
  const float* g2 = (const float*)d_in[7];  const float* b2 = (const float*)d_in[8];
  const float* g3 = (const float*)d_in[9];  const float* b3 = (const float*)d_in[10];
  const float* wfc1 = (const float*)d_in[11]; const float* bfc1 = (const float*)d_in[12];
  const float* wfc2 = (const float*)d_in[13]; const float* bfc2 = (const float*)d_in[14];

  // ---- workspace layout (461 MB total) ----
  char* ws = (char*)d_ws;
  size_t off = 0;
  auto alloc = [&](size_t bytes)->char*{
    char* p = ws + off; off += (bytes + 255) & ~(size_t)255; return p;
  };
  float* xres = (float*)alloc((size_t)NTOK*CC*4);            // 151.0 MB residual (f32)
  u16*   y    = (u16*)  alloc((size_t)NTOK*CC*2);            //  75.5 MB LN out / ctx
  u16*   qkv  = (u16*)  alloc((size_t)NTOK*1536*2);          // 226.5 MB q|k|v ; MLP h overlays
  u16* wqkv1p = (u16*)alloc((size_t)1536*512*2);
  u16* wqkv2p = (u16*)alloc((size_t)1536*512*2);
  u16* wout1p = (u16*)alloc((size_t)512*512*2);
  u16* wout2p = (u16*)alloc((size_t)512*512*2);
  u16* wfc1p  = (u16*)alloc((size_t)2048*512*2);
  u16* wfc2p  = (u16*)alloc((size_t)512*2048*2);
  u16*   hv   = qkv;                                         // MLP hidden (151 MB <= 226.5 MB)

  // ---- d_out doubles as scratch (fully rewritten by k_tout at the end) ----
  // P @ 0 (28.3 MB) ; vt @ 28.3 MB (<=100.7 MB) ; S aliases vt region (S dead
  // before k_vt writes, stream-ordered). Peak 129.0 MB <= 151.0 MB d_out.
  u16*   P    = (u16*)d_out;
  u16*   vt   = (u16*)((char*)d_out + 28311552);
  float* S    = (float*)((char*)d_out + 28311552);
  (void)ws_size; (void)in_sizes; (void)n_in; (void)out_size;

  const float scale = 0.044194173824159216f;   // 1/sqrt(512)

  // weights
  k_permqkv<<<3072, 256, 0, stream>>>(wqkv1, wqkv1p);
  k_permqkv<<<3072, 256, 0, stream>>>(wqkv2, wqkv2p);
  k_conv<<<1024, 256, 0, stream>>>(wout1, wout1p, 512*512);
  k_conv<<<1024, 256, 0, stream>>>(wout2, wout2p, 512*512);
  k_conv<<<4096, 256, 0, stream>>>(wfc1, wfc1p, 2048*512);
  k_conv<<<4096, 256, 0, stream>>>(wfc2, wfc2p, 512*2048);

  // stage 0: layout
  k_tin<<<BB*HH*96, 256, 0, stream>>>(x, xres);

  // ---- attention 1 (along H; seq = (b,w), L=48) ----
  k_ln<<<NTOK/4, 256, 0, stream>>>(xres, g1, b1, y);
  k_gemm<<<576*12, 256, 0, stream>>>(y, 512, wqkv1p, 512, qkv, 1536, nullptr, 512, 12, 0);
  k_qk<<<1536*9, 64, 0, stream>>>(qkv, qkv+512, 1536, S, 48, 3, 192, 9216, 1, 192, scale);
  k_softmax<<<NTOK/4, 256, 0, stream>>>(S, P, 48, 64);
  k_vt<<<1536*16, 256, 0, stream>>>(qkv+1024, 1536, vt, 48, 64, 192, 9216, 1, 192);
  k_pv2<48,64,3,16><<<1536*2, 256, 0, stream>>>(P, vt, y, 192, 9216, 1, 192);
  k_gemm<<<576*4, 256, 0, stream>>>(y, 512, wout1p, 512, xres, 512, nullptr, 512, 4, 2);

  // ---- attention 2 (along W; seq = (b,h), L=192) ----
  k_ln<<<NTOK/4, 256, 0, stream>>>(xres, g2, b2, y);
  k_gemm<<<576*12, 256, 0, stream>>>(y, 512, wqkv2p, 512, qkv, 1536, nullptr, 512, 12, 0);
  k_qk<<<384*144, 64, 0, stream>>>(qkv, qkv+512, 1536, S, 192, 12, 48, 9216, 192, 1, scale);
  k_softmax<<<NTOK/4, 256, 0, stream>>>(S, P, 192, 192);
  k_vt<<<384*16, 256, 0, stream>>>(qkv+1024, 1536, vt, 192, 192, 48, 9216, 192, 1);
  k_pv2<192,192,12,8><<<384*4, 256, 0, stream>>>(P, vt, y, 48, 9216, 192, 1);
  k_gemm<<<576*4, 256, 0, stream>>>(y, 512, wout2p, 512, xres, 512, nullptr, 512, 4, 2);

  // ---- MLP (two K-chunks of 1024 over the 2048 hidden dim) ----
  k_ln<<<NTOK/4, 256, 0, stream>>>(xres, g3, b3, y);
  // chunk 0
  k_gemm<<<576*8, 256, 0, stream>>>(y, 512, wfc1p, 512, hv, 1024, bfc1, 512, 8, 1);
  k_gemm<<<576*4, 256, 0, stream>>>(hv, 1024, wfc2p, 2048, xres, 512, bfc2, 1024, 4, 2);
  // chunk 1
  k_gemm<<<576*8, 256, 0, stream>>>(y, 512, wfc1p + 1024*512, 512, hv, 1024, bfc1 + 1024, 512, 8, 1);
  k_gemm<<<576*4, 256, 0, stream>>>(hv, 1024, wfc2p + 1024, 2048, xres, 512, nullptr, 1024, 4, 2);

  // output layout
  k_tout<<<BB*HH*96, 256, 0, stream>>>(xres, (float*)d_out);
}

// Round 4
// 2180.300 us; speedup vs baseline: 2.5683x; 1.1293x over previous
//
#include <hip/hip_runtime.h>

typedef unsigned short u16;
typedef __attribute__((ext_vector_type(8))) short short8;
typedef __attribute__((ext_vector_type(8))) __bf16 bf16x8;
typedef __attribute__((ext_vector_type(4))) float f32x4;

#define DEV __device__ __forceinline__

// ---------- scalar helpers ----------
DEV u16 f2bf(float f){ unsigned u = __float_as_uint(f); return (u16)((u + 0x7fffu + ((u>>16)&1u)) >> 16); }
DEV float bf2f(u16 h){ return __uint_as_float(((unsigned)h)<<16); }

DEV f32x4 mfma_bf16(short8 a, short8 b, f32x4 c){
  return __builtin_amdgcn_mfma_f32_16x16x32_bf16(
      __builtin_bit_cast(bf16x8, a), __builtin_bit_cast(bf16x8, b), c, 0, 0, 0);
}

DEV void gl2lds16(const u16* g, u16* s){
  __builtin_amdgcn_global_load_lds(
      (__attribute__((address_space(1))) void*)(g),
      (__attribute__((address_space(3))) void*)(s), 16, 0, 0);
}

// problem constants
#define BB 8
#define HH 48
#define WW 192
#define CC 512
#define NTOK (BB*HH*WW)        // 73728

// ---------- weight prep ----------
__global__ void k_permqkv(const float* __restrict__ w, u16* __restrict__ o){
  int i = blockIdx.x*256 + threadIdx.x;          // 1536*512 total
  int n = i >> 9, kk = i & 511;
  int src = 3*(n & 511) + (n >> 9);
  o[i] = f2bf(w[src*512 + kk]);
}
__global__ void k_conv(const float* __restrict__ w, u16* __restrict__ o, int nelem){
  int i = blockIdx.x*256 + threadIdx.x;
  if (i < nelem) o[i] = f2bf(w[i]);
}

// ---------- transpose in: x (B,C,H,W) f32 -> xres (B,H,W,C) f32 ----------
__global__ void k_tin(const float* __restrict__ x, float* __restrict__ xr){
  __shared__ float T[32][33];
  int bh = blockIdx.x / 96, rem = blockIdx.x % 96;
  int c0 = (rem/6)*32, w0 = (rem%6)*32;
  int b = bh / HH, h = bh % HH;
  const float* xp = x + ((size_t)b*CC*HH + h)*WW;     // + c*(HH*WW) + w
  #pragma unroll
  for (int p=0;p<4;p++){
    int idx = p*256 + threadIdx.x;
    int cc = idx >> 5, ww = idx & 31;
    T[cc][ww] = xp[(size_t)(c0+cc)*(HH*WW) + w0 + ww];
  }
  __syncthreads();
  float* xo = xr + (size_t)bh*WW*CC;
  #pragma unroll
  for (int p=0;p<4;p++){
    int idx = p*256 + threadIdx.x;
    int ww = idx >> 5, cc = idx & 31;
    xo[(size_t)(w0+ww)*CC + c0 + cc] = T[cc][ww];
  }
}

// ---------- transpose out: xres (B,H,W,C) f32 -> out (B,C,H,W) f32 ----------
__global__ void k_tout(const float* __restrict__ xr, float* __restrict__ out){
  __shared__ float T[32][33];
  int bh = blockIdx.x / 96, rem = blockIdx.x % 96;
  int c0 = (rem/6)*32, w0 = (rem%6)*32;
  int b = bh / HH, h = bh % HH;
  const float* xi = xr + (size_t)bh*WW*CC;
  #pragma unroll
  for (int p=0;p<4;p++){
    int idx = p*256 + threadIdx.x;
    int ww = idx >> 5, cc = idx & 31;
    T[ww][cc] = xi[(size_t)(w0+ww)*CC + c0 + cc];
  }
  __syncthreads();
  float* op = out + ((size_t)b*CC*HH + h)*WW;
  #pragma unroll
  for (int p=0;p<4;p++){
    int idx = p*256 + threadIdx.x;
    int cc = idx >> 5, ww = idx & 31;
    op[(size_t)(c0+cc)*(HH*WW) + w0 + ww] = T[ww][cc];
  }
}

// ---------- LayerNorm: xres f32 -> y bf16 (wave per token) ----------
__global__ void k_ln(const float* __restrict__ xr, const float* __restrict__ g,
                     const float* __restrict__ bb, u16* __restrict__ y){
  int t = blockIdx.x*4 + (threadIdx.x>>6);
  int lane = threadIdx.x & 63;
  const float* row = xr + (size_t)t*CC + lane*8;
  float v[8];
  *(f32x4*)(v)   = *(const f32x4*)(row);
  *(f32x4*)(v+4) = *(const f32x4*)(row+4);
  float s=0.f, s2=0.f;
  #pragma unroll
  for (int j=0;j<8;j++){ s += v[j]; s2 += v[j]*v[j]; }
  #pragma unroll
  for (int o=32;o;o>>=1){ s += __shfl_xor(s,o); s2 += __shfl_xor(s2,o); }
  float mean = s*(1.f/CC);
  float var  = s2*(1.f/CC) - mean*mean;
  float rs = rsqrtf(var + 1e-5f);
  const float* gp = g + lane*8; const float* bp = bb + lane*8;
  short8 o8;
  #pragma unroll
  for (int j=0;j<8;j++) o8[j] = (short)f2bf((v[j]-mean)*rs*gp[j] + bp[j]);
  *(short8*)(y + (size_t)t*CC + lane*8) = o8;
}

// ---------- GEMM: Out(M x N) = A(M x K) @ Bw(N x K)^T ----------
// BK=64, XOR-swizzled LDS (conflict-free ds_read_b128, global_load_lds-compatible).
// epi 0: store bf16 ; epi 1: store bf16 with bias+relu ; epi 2: f32 Out += acc (+bias)
__global__ __launch_bounds__(256)
void k_gemm(const u16* __restrict__ A, int lda,
            const u16* __restrict__ Bw, int ldb,
            void* __restrict__ Out, int ldo,
            const float* __restrict__ bias,
            int K, int nbn, int epi){
  __shared__ __align__(16) u16 As[128*64];
  __shared__ __align__(16) u16 Bs[128*64];
  int mb = blockIdx.x / nbn, nb = blockIdx.x % nbn;
  int tid = threadIdx.x, lane = tid & 63, wv = tid >> 6;
  size_t m0 = (size_t)mb*128, n0 = (size_t)nb*128;
  // staging: 8 rows per gl2lds16 call; lane -> row lr=lane>>3, swizzled chunk
  int lr = lane >> 3;                         // 0..7 (row within call)
  int cc0 = (lane & 7) ^ lr;                  // global 8-u16 chunk for this lane
  const u16* gA = A  + (m0 + wv*32 + lr)*(size_t)lda + cc0*8;
  const u16* gB = Bw + (n0 + wv*32 + lr)*(size_t)ldb + cc0*8;
  u16* sA = As + wv*32*64;
  u16* sB = Bs + wv*32*64;
  int m = lane & 15, quad = lane >> 4;
  int wm = (wv>>1)*64, wn = (wv&1)*64;
  // swizzled fragment column offsets (u16 units), per ks
  int off0 = ((quad    ) ^ (m & 7))*8;
  int off1 = ((quad + 4) ^ (m & 7))*8;
  f32x4 acc[4][4];
  #pragma unroll
  for (int i=0;i<4;i++)
    #pragma unroll
    for (int j=0;j<4;j++) acc[i][j] = (f32x4){0.f,0.f,0.f,0.f};
  const u16* aB = As + (wm + m)*64;
  const u16* bB = Bs + (wn + m)*64;
  for (int k0 = 0; k0 < K; k0 += 64){
    #pragma unroll
    for (int t=0;t<4;t++){
      gl2lds16(gA + (size_t)(t*8)*lda, sA + t*8*64);
      gl2lds16(gB + (size_t)(t*8)*ldb, sB + t*8*64);
    }
    gA += 64; gB += 64;
    __syncthreads();
    {
      short8 af[4], bf[4];
      #pragma unroll
      for (int i=0;i<4;i++) af[i] = *(const short8*)(aB + i*16*64 + off0);
      #pragma unroll
      for (int j=0;j<4;j++) bf[j] = *(const short8*)(bB + j*16*64 + off0);
      #pragma unroll
      for (int i=0;i<4;i++)
        #pragma unroll
        for (int j=0;j<4;j++)
          acc[i][j] = mfma_bf16(af[i], bf[j], acc[i][j]);
    }
    {
      short8 af[4], bf[4];
      #pragma unroll
      for (int i=0;i<4;i++) af[i] = *(const short8*)(aB + i*16*64 + off1);
      #pragma unroll
      for (int j=0;j<4;j++) bf[j] = *(const short8*)(bB + j*16*64 + off1);
      #pragma unroll
      for (int i=0;i<4;i++)
        #pragma unroll
        for (int j=0;j<4;j++)
          acc[i][j] = mfma_bf16(af[i], bf[j], acc[i][j]);
    }
    __syncthreads();
  }
  if (epi == 2){
    float* O = (float*)Out + (m0 + wm + quad*4)*(size_t)ldo + n0 + wn + m;
    #pragma unroll
    for (int j=0;j<4;j++){
      float bv = bias ? bias[n0 + wn + j*16 + m] : 0.f;
      #pragma unroll
      for (int i=0;i<4;i++)
        #pragma unroll
        for (int r=0;r<4;r++)
          O[(size_t)(i*16+r)*ldo + j*16] += acc[i][j][r] + bv;
    }
  } else {
    u16* O = (u16*)Out + (m0 + wm + quad*4)*(size_t)ldo + n0 + wn + m;
    #pragma unroll
    for (int j=0;j<4;j++){
      float bv = bias ? bias[n0 + wn + j*16 + m] : 0.f;
      #pragma unroll
      for (int i=0;i<4;i++)
        #pragma unroll
        for (int r=0;r<4;r++){
          float v = acc[i][j][r] + bv;
          if (epi == 1) v = fmaxf(v, 0.f);
          O[(size_t)(i*16+r)*ldo + j*16] = f2bf(v);
        }
    }
  }
}

// ---------- QK^T: one wave per 16x16 S tile ----------
__global__ void k_qk(const u16* __restrict__ q, const u16* __restrict__ kp, int ldq,
                     float* __restrict__ S, int L, int nt,
                     int SD, int OUTs, int INN, int LST, float scale){
  int blk = blockIdx.x;
  int s = blk / (nt*nt), tl = blk % (nt*nt);
  int ti = tl / nt, tj = tl % nt;
  int lane = threadIdx.x, m = lane & 15, quad = lane >> 4;
  size_t tokbase = (size_t)(s/SD)*OUTs + (size_t)(s%SD)*INN;
  const u16* qr = q  + (tokbase + (size_t)(ti*16+m)*LST)*ldq + quad*8;
  const u16* kr = kp + (tokbase + (size_t)(tj*16+m)*LST)*ldq + quad*8;
  f32x4 acc = (f32x4){0.f,0.f,0.f,0.f};
  #pragma unroll
  for (int kk=0; kk<CC; kk+=32)
    acc = mfma_bf16(*(const short8*)(qr+kk), *(const short8*)(kr+kk), acc);
  float* Sp = S + (size_t)s*L*L + (size_t)(ti*16 + quad*4)*L + tj*16 + m;
  #pragma unroll
  for (int r=0;r<4;r++) Sp[(size_t)r*L] = acc[r]*scale;
}

// ---------- softmax rows (wave per row), write bf16 P padded to Lp ----------
__global__ void k_softmax(const float* __restrict__ S, u16* __restrict__ P, int L, int Lp){
  int row = blockIdx.x*4 + (threadIdx.x>>6);
  int lane = threadIdx.x & 63;
  const float* sr = S + (size_t)row*L;
  float v0 = (lane      < L) ? sr[lane]      : -3.0e38f;
  float v1 = (lane+64   < L) ? sr[lane+64]   : -3.0e38f;
  float v2 = (lane+128  < L) ? sr[lane+128]  : -3.0e38f;
  float mx = fmaxf(v0, fmaxf(v1, v2));
  #pragma unroll
  for (int o=32;o;o>>=1) mx = fmaxf(mx, __shfl_xor(mx, o));
  float e0 = (lane      < L) ? __expf(v0-mx) : 0.f;
  float e1 = (lane+64   < L) ? __expf(v1-mx) : 0.f;
  float e2 = (lane+128  < L) ? __expf(v2-mx) : 0.f;
  float sm = e0+e1+e2;
  #pragma unroll
  for (int o=32;o;o>>=1) sm += __shfl_xor(sm, o);
  float inv = 1.f/sm;
  u16* pr = P + (size_t)row*Lp;
  if (lane      < Lp) pr[lane]      = f2bf(e0*inv);
  if (lane+64   < Lp) pr[lane+64]   = f2bf(e1*inv);
  if (lane+128  < Lp) pr[lane+128]  = f2bf(e2*inv);
}

// ---------- V transpose per sequence: v rows (l,c) -> vt[s][c][l], zero-pad l to Lp ----------
__global__ void k_vt(const u16* __restrict__ v, int ldv, u16* __restrict__ vt,
                     int L, int Lp, int SD, int OUTs, int INN, int LST){
  __shared__ float T[32*193];
  int s = blockIdx.x >> 4;
  int c0 = (blockIdx.x & 15)*32;
  size_t tokbase = (size_t)(s/SD)*OUTs + (size_t)(s%SD)*INN;
  int pad = Lp + 1;
  for (int idx = threadIdx.x; idx < L*32; idx += 256){
    int l = idx >> 5, cc = idx & 31;
    T[cc*pad + l] = bf2f(v[(tokbase + (size_t)l*LST)*ldv + c0 + cc]);
  }
  __syncthreads();
  u16* vo = vt + ((size_t)s*CC + c0)*Lp;
  for (int idx = threadIdx.x; idx < 32*Lp; idx += 256){
    int cc = idx / Lp, l = idx - cc*Lp;
    vo[idx] = (l < L) ? f2bf(T[cc*pad + l]) : (u16)0;
  }
}

// ---------- PV v2: block (256 thr) per (seq, column-group) with LDS staging ----------
template<int L, int Lp, int NTQ, int NCJ>
__global__ __launch_bounds__(256)
void k_pv2(const u16* __restrict__ P, const u16* __restrict__ vt, u16* __restrict__ ctx,
           int SD, int OUTs, int INN, int LST){
  constexpr int G   = 32 / NCJ;          // blocks per sequence
  constexpr int LPP = Lp + 8;            // padded P row stride (u16)
  constexpr int CW  = NCJ * 16;          // ctx columns per block
  constexpr int CJW = NCJ / 4;           // cj tiles per wave
  constexpr int NKS = Lp / 32;           // K steps per MFMA chain
  constexpr int SHW = (L*LPP > L*CW) ? L*LPP : L*CW;
  __shared__ __align__(16) u16 SH[SHW];

  int sq = blockIdx.x / G, g = blockIdx.x % G;
  int tid = threadIdx.x, lane = tid & 63, wv = tid >> 6;
  int m = lane & 15, quad = lane >> 4;

  const u16* Pg = P + (size_t)sq * L * Lp;
  constexpr int PU = L * Lp / 8;
  for (int u = tid; u < PU; u += 256){
    int r = u / (Lp/8), c = u % (Lp/8);
    *(short8*)(SH + r*LPP + c*8) = *(const short8*)(Pg + (size_t)r*Lp + c*8);
  }
  __syncthreads();

  short8 bfr[CJW][NKS];
  #pragma unroll
  for (int lc = 0; lc < CJW; lc++){
    const u16* vr = vt + ((size_t)sq*CC + (size_t)((g*NCJ + (wv*CJW + lc))*16 + m))*Lp + quad*8;
    #pragma unroll
    for (int ks = 0; ks < NKS; ks++) bfr[lc][ks] = *(const short8*)(vr + ks*32);
  }

  f32x4 acc[CJW][NTQ];
  #pragma unroll
  for (int lc = 0; lc < CJW; lc++)
    #pragma unroll
    for (int qt = 0; qt < NTQ; qt++) acc[lc][qt] = (f32x4){0.f,0.f,0.f,0.f};

  #pragma unroll
  for (int qt = 0; qt < NTQ; qt++){
    short8 a[NKS];
    #pragma unroll
    for (int ks = 0; ks < NKS; ks++)
      a[ks] = *(const short8*)(SH + (qt*16 + m)*LPP + quad*8 + ks*32);
    #pragma unroll
    for (int lc = 0; lc < CJW; lc++)
      #pragma unroll
      for (int ks = 0; ks < NKS; ks++)
        acc[lc][qt] = mfma_bf16(a[ks], bfr[lc][ks], acc[lc][qt]);
  }
  __syncthreads();

  #pragma unroll
  for (int qt = 0; qt < NTQ; qt++)
    #pragma unroll
    for (int lc = 0; lc < CJW; lc++)
      #pragma unroll
      for (int r = 0; r < 4; r++)
        SH[(qt*16 + quad*4 + r)*CW + (wv*CJW + lc)*16 + m] = f2bf(acc[lc][qt][r]);
  __syncthreads();

  size_t tokbase = (size_t)(sq/SD)*OUTs + (size_t)(sq%SD)*INN;
  constexpr int CU8 = CW / 8;
  constexpr int TU = L * CU8;
  for (int u = tid; u < TU; u += 256){
    int l = u / CU8, c = u % CU8;
    *(short8*)(ctx + (tokbase + (size_t)l*LST)*CC + g*CW + c*8) =
        *(const short8*)(SH + l*CW + c*8);
  }
}

// =======================================================================
extern "C" void kernel_launch(void* const* d_in, const int* in_sizes, int n_in,
                              void* d_out, int out_size, void* d_ws, size_t ws_size,
                              hipStream_t stream){
  const float* x      = (const float*)d_in[0];
  const float* wqkv1  = (const float*)d_in[1];
  const float* wout1  = (const float*)d_in[2];
  const float* wqkv2  = (const float*)d_in[3];
  const float* wout2  = (const float*)d_in[4];
  const float* g1 = (const float*)d_in[5];  const float* b1 = (const float*)d_in[6];
  const float* g2 = (const float*)d_in[7];  const float* b2 = (const float*)d_in[8];
  const float* g3 = (const float*)d_in[9];  const float* b3 = (const float*)d_in[10];
  const float* wfc1 = (const float*)d_in[11]; const float* bfc1 = (const float*)d_in[12];
  const float* wfc2 = (const float*)d_in[13]; const float* bfc2 = (const float*)d_in[14];

  // ---- workspace layout (461 MB total) ----
  char* ws = (char*)d_ws;
  size_t off = 0;
  auto alloc = [&](size_t bytes)->char*{
    char* p = ws + off; off += (bytes + 255) & ~(size_t)255; return p;
  };
  float* xres = (float*)alloc((size_t)NTOK*CC*4);            // 151.0 MB residual (f32)
  u16*   y    = (u16*)  alloc((size_t)NTOK*CC*2);            //  75.5 MB LN out / ctx
  u16*   qkv  = (u16*)  alloc((size_t)NTOK*1536*2);          // 226.5 MB q|k|v ; MLP h overlays
  u16* wqkv1p = (u16*)alloc((size_t)1536*512*2);
  u16* wqkv2p = (u16*)alloc((size_t)1536*512*2);
  u16* wout1p = (u16*)alloc((size_t)512*512*2);
  u16* wout2p = (u16*)alloc((size_t)512*512*2);
  u16* wfc1p  = (u16*)alloc((size_t)2048*512*2);
  u16* wfc2p  = (u16*)alloc((size_t)512*2048*2);
  u16*   hv   = qkv;                                         // MLP hidden half (151 MB <= 226.5 MB)

  // ---- d_out doubles as scratch (fully rewritten by k_tout at the end) ----
  u16*   P    = (u16*)d_out;
  u16*   vt   = (u16*)((char*)d_out + 28311552);
  float* S    = (float*)((char*)d_out + 28311552);
  (void)ws_size; (void)in_sizes; (void)n_in; (void)out_size;

  const float scale = 0.044194173824159216f;   // 1/sqrt(512)

  // weights
  k_permqkv<<<3072, 256, 0, stream>>>(wqkv1, wqkv1p);
  k_permqkv<<<3072, 256, 0, stream>>>(wqkv2, wqkv2p);
  k_conv<<<1024, 256, 0, stream>>>(wout1, wout1p, 512*512);
  k_conv<<<1024, 256, 0, stream>>>(wout2, wout2p, 512*512);
  k_conv<<<4096, 256, 0, stream>>>(wfc1, wfc1p, 2048*512);
  k_conv<<<4096, 256, 0, stream>>>(wfc2, wfc2p, 512*2048);

  // stage 0: layout
  k_tin<<<BB*HH*96, 256, 0, stream>>>(x, xres);

  // ---- attention 1 (along H; seq = (b,w), L=48) ----
  k_ln<<<NTOK/4, 256, 0, stream>>>(xres, g1, b1, y);
  k_gemm<<<576*12, 256, 0, stream>>>(y, 512, wqkv1p, 512, qkv, 1536, nullptr, 512, 12, 0);
  k_qk<<<1536*9, 64, 0, stream>>>(qkv, qkv+512, 1536, S, 48, 3, 192, 9216, 1, 192, scale);
  k_softmax<<<NTOK/4, 256, 0, stream>>>(S, P, 48, 64);
  k_vt<<<1536*16, 256, 0, stream>>>(qkv+1024, 1536, vt, 48, 64, 192, 9216, 1, 192);
  k_pv2<48,64,3,16><<<1536*2, 256, 0, stream>>>(P, vt, y, 192, 9216, 1, 192);
  k_gemm<<<576*4, 256, 0, stream>>>(y, 512, wout1p, 512, xres, 512, nullptr, 512, 4, 2);

  // ---- attention 2 (along W; seq = (b,h), L=192) ----
  k_ln<<<NTOK/4, 256, 0, stream>>>(xres, g2, b2, y);
  k_gemm<<<576*12, 256, 0, stream>>>(y, 512, wqkv2p, 512, qkv, 1536, nullptr, 512, 12, 0);
  k_qk<<<384*144, 64, 0, stream>>>(qkv, qkv+512, 1536, S, 192, 12, 48, 9216, 192, 1, scale);
  k_softmax<<<NTOK/4, 256, 0, stream>>>(S, P, 192, 192);
  k_vt<<<384*16, 256, 0, stream>>>(qkv+1024, 1536, vt, 192, 192, 48, 9216, 192, 1);
  k_pv2<192,192,12,8><<<384*4, 256, 0, stream>>>(P, vt, y, 48, 9216, 192, 1);
  k_gemm<<<576*4, 256, 0, stream>>>(y, 512, wout2p, 512, xres, 512, nullptr, 512, 4, 2);

  // ---- MLP: two M-halves, each fc1 (full N=2048) then fc2 (single K=2048 pass) ----
  k_ln<<<NTOK/4, 256, 0, stream>>>(xres, g3, b3, y);
  for (int half = 0; half < 2; half++){
    size_t M0 = (size_t)half * 36864;
    k_gemm<<<288*16, 256, 0, stream>>>(y + M0*512, 512, wfc1p, 512, hv, 2048, bfc1, 512, 16, 1);
    k_gemm<<<288*4, 256, 0, stream>>>(hv, 2048, wfc2p, 2048, xres + M0*512, 512, bfc2, 2048, 4, 2);
  }

  // output layout
  k_tout<<<BB*HH*96, 256, 0, stream>>>(xres, (float*)d_out);
}